// Round 1
// baseline (397.152 us; speedup 1.0000x reference)
//
#include <hip/hip_runtime.h>

// TreeLSTM cell fused as one bf16-MFMA GEMM + gated epilogue.
// pre[n][j] = [x[n] | child_h[idx[n]]] (K=512)  @  [Wiou|Wf ; Uiou|Uf].T (1024 cols) + bias
// j layout: seg0=i, seg1=o, seg2=u, seg3=f-gate. Block = 128 rows x (4 segs x 64 h-cols of group g).

typedef unsigned short u16;
typedef unsigned int u32;
typedef __bf16 bf16x8 __attribute__((ext_vector_type(8)));
typedef float f32x16 __attribute__((ext_vector_type(16)));
typedef u16 u16x4 __attribute__((ext_vector_type(4)));
typedef u16 u16x8 __attribute__((ext_vector_type(8)));

#define NTOT 131072
#define NHOFF (131072 * 256)

__device__ __forceinline__ u16 f2bf(float f) {
  u32 u = __float_as_uint(f);
  return (u16)((u + 0x7FFFu + ((u >> 16) & 1u)) >> 16);  // RNE
}

// Pack Wcat[1024][512] -> bf16, per (group g, k-tile kt) regions of 256x64,
// stored as the exact swizzled LDS image: slot = (c*8 + k8) ^ (c&7)  (16B slots).
__global__ void prep_w(const float* __restrict__ Wiou, const float* __restrict__ Uiou,
                       const float* __restrict__ Wf, const float* __restrict__ Uf,
                       u16* __restrict__ Bpack) {
  int cid = blockIdx.x * 256 + threadIdx.x;  // 65536 chunks of 8
  int j = cid >> 6;
  int kc = cid & 63;
  int k = kc * 8;
  int kt = kc >> 3, k8 = kc & 7;
  int s = j >> 8, g = (j >> 6) & 3, e = j & 63;
  int c = s * 64 + e;  // block-col within a group's 256-wide tile
  const float* src;
  if (j < 768) src = (k < 256) ? (Wiou + j * 256 + k) : (Uiou + j * 256 + (k - 256));
  else { int jj = j - 768; src = (k < 256) ? (Wf + jj * 256 + k) : (Uf + jj * 256 + (k - 256)); }
  float4 f0 = *(const float4*)(src);
  float4 f1 = *(const float4*)(src + 4);
  u16x8 v;
  v[0] = f2bf(f0.x); v[1] = f2bf(f0.y); v[2] = f2bf(f0.z); v[3] = f2bf(f0.w);
  v[4] = f2bf(f1.x); v[5] = f2bf(f1.y); v[6] = f2bf(f1.z); v[7] = f2bf(f1.w);
  int slot = (g * 8 + kt) * 2048 + ((c * 8 + k8) ^ (c & 7));
  *(u16x8*)(Bpack + slot * 8) = v;
}

__global__ void prep_bias(const float* __restrict__ biou, const float* __restrict__ wfb,
                          const float* __restrict__ ufb, const float* __restrict__ bfv,
                          float* __restrict__ Bias) {
  int j = blockIdx.x * 256 + threadIdx.x;  // 1024 exact
  Bias[j] = (j < 768) ? biou[j] : (wfb[j - 768] + ufb[j - 768] + bfv[j - 768]);
}

__global__ __launch_bounds__(256, 2)
void treelstm_main(const float* __restrict__ x, const float* __restrict__ child_h,
                   const float* __restrict__ child_c, const int* __restrict__ cidx,
                   const u16* __restrict__ Bpack, const float* __restrict__ Bias,
                   float* __restrict__ out) {
  __shared__ __align__(16) u16 ldsA[128 * 64];   // 16 KB, swizzled rows (stride 128B)
  __shared__ __align__(16) u16 ldsB[256 * 64];   // 32 KB, swizzled rows
  __shared__ int lds_cidx[128];

  const int tid = threadIdx.x;
  const int n0 = blockIdx.x * 128;
  const int g = blockIdx.y;

  if (tid < 128) lds_cidx[tid] = cidx[n0 + tid];

  const int lane = tid & 63, w = tid >> 6;
  const int wm = w >> 1, wn = w & 1;       // 2M x 2N wave grid; wave = 64 rows x (4 segs x 32 cols)
  const int lr = lane & 31, hi = lane >> 5;

  f32x16 acc[2][4] = {};                    // [mi][seg]

  const char* ldsAb = (const char*)ldsA;
  const char* ldsBb = (const char*)ldsB;
  int arow[2];
  #pragma unroll
  for (int mi = 0; mi < 2; mi++) arow[mi] = (wm * 64 + mi * 32 + lr) * 128;
  const int aswz = (lr & 7) << 4;           // r&7 == lr&7 (bases are multiples of 8)
  int brow[4];
  #pragma unroll
  for (int s = 0; s < 4; s++) brow[s] = (s * 64 + wn * 32 + lr) * 128;
  const int bswz = (lr & 7) << 4;

  for (int kt = 0; kt < 8; ++kt) {
    // --- stage A: 128x64 f32 -> bf16, swizzled ds_write (kt<4: x, else gathered child_h)
    #pragma unroll
    for (int q = 0; q < 8; ++q) {
      int v = q * 256 + tid;
      int r = v >> 4;
      int kq = (v & 15) * 4;
      const float* src = (kt < 4) ? (x + (n0 + r) * 256 + kt * 64 + kq)
                                  : (child_h + lds_cidx[r] * 256 + (kt - 4) * 64 + kq);
      float4 d = *(const float4*)src;
      u16x4 b;
      b[0] = f2bf(d.x); b[1] = f2bf(d.y); b[2] = f2bf(d.z); b[3] = f2bf(d.w);
      int addr = (r * 128 + kq * 2) ^ ((r & 7) << 4);
      *(u16x4*)((char*)ldsA + addr) = b;
    }
    // --- stage B: linear copy of pre-swizzled image (256x64 bf16 = 32KB)
    const u16* bsrc = Bpack + (g * 8 + kt) * 16384;
    #pragma unroll
    for (int q = 0; q < 8; ++q) {
      int m = q * 256 + tid;
      *(u16x8*)((char*)ldsB + m * 16) = *(const u16x8*)(bsrc + m * 8);
    }
    __syncthreads();
    // --- compute: 4 k-substeps of K=16
    #pragma unroll
    for (int ks = 0; ks < 4; ++ks) {
      int kb = ks * 32 + hi * 16;
      bf16x8 af[2], bfr[4];
      #pragma unroll
      for (int mi = 0; mi < 2; mi++)
        af[mi] = *(const bf16x8*)(ldsAb + ((arow[mi] + kb) ^ aswz));
      #pragma unroll
      for (int s = 0; s < 4; s++)
        bfr[s] = *(const bf16x8*)(ldsBb + ((brow[s] + kb) ^ bswz));
      #pragma unroll
      for (int mi = 0; mi < 2; mi++)
        #pragma unroll
        for (int s = 0; s < 4; s++)
          acc[mi][s] = __builtin_amdgcn_mfma_f32_32x32x16_bf16(af[mi], bfr[s], acc[mi][s], 0, 0, 0);
    }
    __syncthreads();
  }

  // --- epilogue: each lane holds i,o,u,f for the same (row,col) -> no shuffles
  const int tcol = g * 64 + wn * 32 + lr;
  const float bi = Bias[tcol], bo = Bias[256 + tcol], bu = Bias[512 + tcol], bfg = Bias[768 + tcol];
  #pragma unroll
  for (int mi = 0; mi < 2; mi++) {
    #pragma unroll
    for (int reg = 0; reg < 16; ++reg) {
      int row = wm * 64 + mi * 32 + (reg & 3) + 8 * (reg >> 2) + 4 * hi;  // m74/m101 C/D map
      int n = n0 + row;
      float i_ = acc[mi][0][reg] + bi;
      float o_ = acc[mi][1][reg] + bo;
      float u_ = acc[mi][2][reg] + bu;
      float fp = acc[mi][3][reg] + bfg;
      float ccv = child_c[lds_cidx[row] * 256 + tcol];
      float sigi = 1.f / (1.f + __expf(-i_));
      float sigo = 1.f / (1.f + __expf(-o_));
      float sigf = 1.f / (1.f + __expf(-fp));
      float tu = 2.f / (1.f + __expf(-2.f * u_)) - 1.f;
      float c = sigi * tu + sigf * ccv;
      float tc = 2.f / (1.f + __expf(-2.f * c)) - 1.f;
      out[n * 256 + tcol] = sigo * tc;
      out[NHOFF + n * 256 + tcol] = c;
    }
  }
}

extern "C" void kernel_launch(void* const* d_in, const int* in_sizes, int n_in,
                              void* d_out, int out_size, void* d_ws, size_t ws_size,
                              hipStream_t stream) {
  const float* x    = (const float*)d_in[0];
  const float* ch   = (const float*)d_in[1];
  const float* cc   = (const float*)d_in[2];
  const int*   ci   = (const int*)d_in[3];
  const float* Wiou = (const float*)d_in[4];
  const float* Uiou = (const float*)d_in[5];
  const float* biou = (const float*)d_in[6];
  const float* Wf   = (const float*)d_in[7];
  const float* Wfb  = (const float*)d_in[8];
  const float* Uf   = (const float*)d_in[9];
  const float* Ufb  = (const float*)d_in[10];
  const float* bfv  = (const float*)d_in[11];

  u16* Bpack = (u16*)d_ws;                              // 1 MB bf16 packed weights
  float* Bias = (float*)((char*)d_ws + (1 << 20));      // 4 KB combined bias

  prep_w<<<256, 256, 0, stream>>>(Wiou, Uiou, Wf, Uf, Bpack);
  prep_bias<<<4, 256, 0, stream>>>(biou, Wfb, Ufb, bfv, Bias);
  dim3 grid(1024, 4);
  treelstm_main<<<grid, 256, 0, stream>>>(x, ch, cc, ci, Bpack, Bias, (float*)d_out);
}

// Round 2
// 318.596 us; speedup vs baseline: 1.2466x; 1.2466x over previous
//
#include <hip/hip_runtime.h>

// TreeLSTM cell fused as one bf16-MFMA GEMM + gated epilogue.
// pre[n][j] = [x[n] | child_h[idx[n]]] (K=512) @ [Wiou|Wf ; Uiou|Uf].T (1024 cols) + bias
// j layout: seg0=i, seg1=o, seg2=u, seg3=f-gate. Block = 128 rows x (4 segs x 64 h-cols of group g).
// Fast path: prep pass packs A=[x|hc] as bf16 row-major in d_ws; main loop stages A and B
// purely via global_load_lds width=16 (linear LDS dest, XOR-swizzle applied on the global
// source address and on the LDS read side -- rule #21 both-sides-or-neither).

typedef unsigned short u16;
typedef unsigned int u32;
typedef __bf16 bf16x8 __attribute__((ext_vector_type(8)));
typedef float f32x16 __attribute__((ext_vector_type(16)));
typedef u16 u16x4 __attribute__((ext_vector_type(4)));
typedef u16 u16x8 __attribute__((ext_vector_type(8)));

#define NTOT 131072
#define NHOFF (131072 * 256)

__device__ __forceinline__ u16 f2bf(float f) {
  u32 u = __float_as_uint(f);
  return (u16)((u + 0x7FFFu + ((u >> 16) & 1u)) >> 16);  // RNE
}

// Pack Wcat[1024][512] -> bf16, per (group g, k-tile kt) regions of 256x64,
// stored as the exact swizzled LDS image: slot = (c*8 + k8) ^ (c&7)  (16B slots).
__global__ void prep_w(const float* __restrict__ Wiou, const float* __restrict__ Uiou,
                       const float* __restrict__ Wf, const float* __restrict__ Uf,
                       u16* __restrict__ Bpack) {
  int cid = blockIdx.x * 256 + threadIdx.x;  // 65536 chunks of 8
  int j = cid >> 6;
  int kc = cid & 63;
  int k = kc * 8;
  int kt = kc >> 3, k8 = kc & 7;
  int s = j >> 8, g = (j >> 6) & 3, e = j & 63;
  int c = s * 64 + e;  // block-col within a group's 256-wide tile
  const float* src;
  if (j < 768) src = (k < 256) ? (Wiou + j * 256 + k) : (Uiou + j * 256 + (k - 256));
  else { int jj = j - 768; src = (k < 256) ? (Wf + jj * 256 + k) : (Uf + jj * 256 + (k - 256)); }
  float4 f0 = *(const float4*)(src);
  float4 f1 = *(const float4*)(src + 4);
  u16x8 v;
  v[0] = f2bf(f0.x); v[1] = f2bf(f0.y); v[2] = f2bf(f0.z); v[3] = f2bf(f0.w);
  v[4] = f2bf(f1.x); v[5] = f2bf(f1.y); v[6] = f2bf(f1.z); v[7] = f2bf(f1.w);
  int slot = (g * 8 + kt) * 2048 + ((c * 8 + k8) ^ (c & 7));
  *(u16x8*)(Bpack + slot * 8) = v;
}

__global__ void prep_bias(const float* __restrict__ biou, const float* __restrict__ wfb,
                          const float* __restrict__ ufb, const float* __restrict__ bfv,
                          float* __restrict__ Bias) {
  int j = blockIdx.x * 256 + threadIdx.x;  // 1024 exact
  Bias[j] = (j < 768) ? biou[j] : (wfb[j - 768] + ufb[j - 768] + bfv[j - 768]);
}

// Apack[n] = [ x[n] (512B bf16) | child_h[idx[n]] (512B bf16) ], plain row-major.
__global__ void prep_apack(const float* __restrict__ x, const float* __restrict__ ch,
                           const int* __restrict__ cidx, u16* __restrict__ Apack) {
  int e = blockIdx.x * 256 + threadIdx.x;  // 8.39M threads: 131072 rows x 64 chunks of 8
  int n = e >> 6, c = e & 63;
  const float* src = (c < 32) ? (x + (size_t)n * 256 + c * 8)
                              : (ch + (size_t)cidx[n] * 256 + (c - 32) * 8);
  float4 f0 = *(const float4*)src;
  float4 f1 = *(const float4*)(src + 4);
  u16x8 v;
  v[0] = f2bf(f0.x); v[1] = f2bf(f0.y); v[2] = f2bf(f0.z); v[3] = f2bf(f0.w);
  v[4] = f2bf(f1.x); v[5] = f2bf(f1.y); v[6] = f2bf(f1.z); v[7] = f2bf(f1.w);
  *(u16x8*)(Apack + (size_t)n * 512 + c * 8) = v;
}

// ---------- fast main: all staging via global_load_lds (width=16) ----------
__global__ __launch_bounds__(256, 2)
void treelstm_main_bf16(const u16* __restrict__ Apack, const u16* __restrict__ Bpack,
                        const float* __restrict__ Bias, const float* __restrict__ child_c,
                        const int* __restrict__ cidx, float* __restrict__ out) {
  __shared__ __align__(16) u16 ldsA[128 * 64];   // 16 KB, swizzled image (stride 128B rows)
  __shared__ __align__(16) u16 ldsB[256 * 64];   // 32 KB, swizzled image
  __shared__ int lds_cidx[128];

  const int tid = threadIdx.x;
  const int n0 = blockIdx.x * 128;
  const int g = blockIdx.y;

  if (tid < 128) lds_cidx[tid] = cidx[n0 + tid];  // epilogue only; barriers below cover it

  const int lane = tid & 63, w = tid >> 6;
  const int wm = w >> 1, wn = w & 1;       // 2M x 2N wave grid; wave = 64 rows x (4 segs x 32 cols)
  const int lr = lane & 31, hi = lane >> 5;

  f32x16 acc[2][4] = {};                    // [mi][seg]

  // Per-lane staging sources. A slot m = w*256+q*64+lane -> row r = w*32+q*8+(lane>>3),
  // 16B-slot s = lane&7; source slot pre-swizzled: s ^ (r&7).
  const char* aP = (const char*)Apack
      + (size_t)(n0 + w * 32 + (lane >> 3)) * 1024
      + (((lane & 7) ^ ((lane >> 3) & 7)) << 4);
  // B slot = w*512+q*64+lane, linear (Bpack image is pre-swizzled).
  const char* bP = (const char*)Bpack + (size_t)g * 262144 + ((w * 512 + lane) << 4);

  char* ldsAw = (char*)ldsA + w * 4096;   // wave-uniform LDS bases (HW adds lane*16)
  char* ldsBw = (char*)ldsB + w * 8192;

  const char* ldsAb = (const char*)ldsA;
  const char* ldsBb = (const char*)ldsB;
  int arow[2];
  #pragma unroll
  for (int mi = 0; mi < 2; mi++) arow[mi] = (wm * 64 + mi * 32 + lr) * 128;
  const int aswz = (lr & 7) << 4;
  int brow[4];
  #pragma unroll
  for (int s = 0; s < 4; s++) brow[s] = (s * 64 + wn * 32 + lr) * 128;
  const int bswz = (lr & 7) << 4;

  #pragma unroll 1
  for (int kt = 0; kt < 8; ++kt) {
    // --- stage A: 4 x global_load_lds (16B/lane); source addr carries the swizzle
    #pragma unroll
    for (int q = 0; q < 4; ++q)
      __builtin_amdgcn_global_load_lds(
          (const __attribute__((address_space(1))) void*)(aP + q * 8192),
          (__attribute__((address_space(3))) void*)(ldsAw + q * 1024), 16, 0, 0);
    // --- stage B: 8 x global_load_lds, fully linear (image pre-swizzled in ws)
    #pragma unroll
    for (int q = 0; q < 8; ++q)
      __builtin_amdgcn_global_load_lds(
          (const __attribute__((address_space(1))) void*)(bP + q * 1024),
          (__attribute__((address_space(3))) void*)(ldsBw + q * 1024), 16, 0, 0);
    __syncthreads();  // compiler drains vmcnt before s_barrier -> LDS ready
    // --- compute: 4 k-substeps of K=16
    #pragma unroll
    for (int ks = 0; ks < 4; ++ks) {
      int kb = ks * 32 + hi * 16;
      bf16x8 af[2], bfr[4];
      #pragma unroll
      for (int mi = 0; mi < 2; mi++)
        af[mi] = *(const bf16x8*)(ldsAb + ((arow[mi] + kb) ^ aswz));
      #pragma unroll
      for (int s = 0; s < 4; s++)
        bfr[s] = *(const bf16x8*)(ldsBb + ((brow[s] + kb) ^ bswz));
      #pragma unroll
      for (int mi = 0; mi < 2; mi++)
        #pragma unroll
        for (int s = 0; s < 4; s++)
          acc[mi][s] = __builtin_amdgcn_mfma_f32_32x32x16_bf16(af[mi], bfr[s], acc[mi][s], 0, 0, 0);
    }
    __syncthreads();
    aP += 128;      // next 64-K slice within the 1024B row
    bP += 32768;    // next pre-swizzled 32KB B tile
  }

  // --- epilogue: each lane holds i,o,u,f for the same (row,col) -> no shuffles
  const int tcol = g * 64 + wn * 32 + lr;
  const float bi = Bias[tcol], bo = Bias[256 + tcol], bu = Bias[512 + tcol], bfg = Bias[768 + tcol];
  #pragma unroll
  for (int mi = 0; mi < 2; mi++) {
    #pragma unroll
    for (int reg = 0; reg < 16; ++reg) {
      int row = wm * 64 + mi * 32 + (reg & 3) + 8 * (reg >> 2) + 4 * hi;  // m74/m101 C/D map
      int n = n0 + row;
      float i_ = acc[mi][0][reg] + bi;
      float o_ = acc[mi][1][reg] + bo;
      float u_ = acc[mi][2][reg] + bu;
      float fp = acc[mi][3][reg] + bfg;
      float ccv = child_c[(size_t)lds_cidx[row] * 256 + tcol];
      float sigi = 1.f / (1.f + __expf(-i_));
      float sigo = 1.f / (1.f + __expf(-o_));
      float sigf = 1.f / (1.f + __expf(-fp));
      float tu = 2.f / (1.f + __expf(-2.f * u_)) - 1.f;
      float c = sigi * tu + sigf * ccv;
      float tc = 2.f / (1.f + __expf(-2.f * c)) - 1.f;
      out[(size_t)n * 256 + tcol] = sigo * tc;
      out[NHOFF + (size_t)n * 256 + tcol] = c;
    }
  }
}

// ---------- fallback main (round-1 proven path, used if ws too small) ----------
__global__ __launch_bounds__(256, 2)
void treelstm_main_f32(const float* __restrict__ x, const float* __restrict__ child_h,
                       const float* __restrict__ child_c, const int* __restrict__ cidx,
                       const u16* __restrict__ Bpack, const float* __restrict__ Bias,
                       float* __restrict__ out) {
  __shared__ __align__(16) u16 ldsA[128 * 64];
  __shared__ __align__(16) u16 ldsB[256 * 64];
  __shared__ int lds_cidx[128];

  const int tid = threadIdx.x;
  const int n0 = blockIdx.x * 128;
  const int g = blockIdx.y;

  if (tid < 128) lds_cidx[tid] = cidx[n0 + tid];

  const int lane = tid & 63, w = tid >> 6;
  const int wm = w >> 1, wn = w & 1;
  const int lr = lane & 31, hi = lane >> 5;

  f32x16 acc[2][4] = {};

  const char* ldsAb = (const char*)ldsA;
  const char* ldsBb = (const char*)ldsB;
  int arow[2];
  #pragma unroll
  for (int mi = 0; mi < 2; mi++) arow[mi] = (wm * 64 + mi * 32 + lr) * 128;
  const int aswz = (lr & 7) << 4;
  int brow[4];
  #pragma unroll
  for (int s = 0; s < 4; s++) brow[s] = (s * 64 + wn * 32 + lr) * 128;
  const int bswz = (lr & 7) << 4;

  for (int kt = 0; kt < 8; ++kt) {
    #pragma unroll
    for (int q = 0; q < 8; ++q) {
      int v = q * 256 + tid;
      int r = v >> 4;
      int kq = (v & 15) * 4;
      const float* src = (kt < 4) ? (x + (size_t)(n0 + r) * 256 + kt * 64 + kq)
                                  : (child_h + (size_t)lds_cidx[r] * 256 + (kt - 4) * 64 + kq);
      float4 d = *(const float4*)src;
      u16x4 b;
      b[0] = f2bf(d.x); b[1] = f2bf(d.y); b[2] = f2bf(d.z); b[3] = f2bf(d.w);
      int addr = (r * 128 + kq * 2) ^ ((r & 7) << 4);
      *(u16x4*)((char*)ldsA + addr) = b;
    }
    const u16* bsrc = Bpack + (g * 8 + kt) * 16384;
    #pragma unroll
    for (int q = 0; q < 8; ++q) {
      int m = q * 256 + tid;
      *(u16x8*)((char*)ldsB + m * 16) = *(const u16x8*)(bsrc + m * 8);
    }
    __syncthreads();
    #pragma unroll
    for (int ks = 0; ks < 4; ++ks) {
      int kb = ks * 32 + hi * 16;
      bf16x8 af[2], bfr[4];
      #pragma unroll
      for (int mi = 0; mi < 2; mi++)
        af[mi] = *(const bf16x8*)(ldsAb + ((arow[mi] + kb) ^ aswz));
      #pragma unroll
      for (int s = 0; s < 4; s++)
        bfr[s] = *(const bf16x8*)(ldsBb + ((brow[s] + kb) ^ bswz));
      #pragma unroll
      for (int mi = 0; mi < 2; mi++)
        #pragma unroll
        for (int s = 0; s < 4; s++)
          acc[mi][s] = __builtin_amdgcn_mfma_f32_32x32x16_bf16(af[mi], bfr[s], acc[mi][s], 0, 0, 0);
    }
    __syncthreads();
  }

  const int tcol = g * 64 + wn * 32 + lr;
  const float bi = Bias[tcol], bo = Bias[256 + tcol], bu = Bias[512 + tcol], bfg = Bias[768 + tcol];
  #pragma unroll
  for (int mi = 0; mi < 2; mi++) {
    #pragma unroll
    for (int reg = 0; reg < 16; ++reg) {
      int row = wm * 64 + mi * 32 + (reg & 3) + 8 * (reg >> 2) + 4 * hi;
      int n = n0 + row;
      float i_ = acc[mi][0][reg] + bi;
      float o_ = acc[mi][1][reg] + bo;
      float u_ = acc[mi][2][reg] + bu;
      float fp = acc[mi][3][reg] + bfg;
      float ccv = child_c[(size_t)lds_cidx[row] * 256 + tcol];
      float sigi = 1.f / (1.f + __expf(-i_));
      float sigo = 1.f / (1.f + __expf(-o_));
      float sigf = 1.f / (1.f + __expf(-fp));
      float tu = 2.f / (1.f + __expf(-2.f * u_)) - 1.f;
      float c = sigi * tu + sigf * ccv;
      float tc = 2.f / (1.f + __expf(-2.f * c)) - 1.f;
      out[(size_t)n * 256 + tcol] = sigo * tc;
      out[NHOFF + (size_t)n * 256 + tcol] = c;
    }
  }
}

extern "C" void kernel_launch(void* const* d_in, const int* in_sizes, int n_in,
                              void* d_out, int out_size, void* d_ws, size_t ws_size,
                              hipStream_t stream) {
  const float* x    = (const float*)d_in[0];
  const float* ch   = (const float*)d_in[1];
  const float* cc   = (const float*)d_in[2];
  const int*   ci   = (const int*)d_in[3];
  const float* Wiou = (const float*)d_in[4];
  const float* Uiou = (const float*)d_in[5];
  const float* biou = (const float*)d_in[6];
  const float* Wf   = (const float*)d_in[7];
  const float* Wfb  = (const float*)d_in[8];
  const float* Uf   = (const float*)d_in[9];
  const float* Ufb  = (const float*)d_in[10];
  const float* bfv  = (const float*)d_in[11];

  u16* Bpack = (u16*)d_ws;                              // 1 MB bf16 packed weights
  float* Bias = (float*)((char*)d_ws + (1 << 20));      // 4 KB combined bias
  u16* Apack = (u16*)((char*)d_ws + (2 << 20));         // 134.2 MB packed [x|hc] bf16

  const size_t need = (size_t)(2 << 20) + (size_t)NTOT * 512 * sizeof(u16);

  prep_w<<<256, 256, 0, stream>>>(Wiou, Uiou, Wf, Uf, Bpack);
  prep_bias<<<4, 256, 0, stream>>>(biou, Wfb, Ufb, bfv, Bias);

  dim3 grid(1024, 4);
  if (ws_size >= need) {
    prep_apack<<<32768, 256, 0, stream>>>(x, ch, ci, Apack);
    treelstm_main_bf16<<<grid, 256, 0, stream>>>(Apack, Bpack, Bias, cc, ci, (float*)d_out);
  } else {
    treelstm_main_f32<<<grid, 256, 0, stream>>>(x, ch, cc, ci, Bpack, Bias, (float*)d_out);
  }
}